// Round 3
// baseline (846.989 us; speedup 1.0000x reference)
//
#include <hip/hip_runtime.h>

// RGAT encoder, 2 layers. N=32768, E=160000, DIM=768, R=3, heads 4 then 1.
// Round 7 (from 653 us): R5/R6 both pinned at ~38% MfmaUtil regardless of
// occupancy (19% vs 40%) -> LDS-read-bound structure (64x64 wave tile =
// 31 B/KFLOP; per-CU round LDS 1920 cyc > MFMA 1242 cyc). This round cuts
// LDS traffic per FLOP instead of re-tuning the schedule:
//  - 32x32x16 MFMA (2495 vs 2075 TF ceiling), wave tile 128x64 (4x2 tiles)
//  - B (3.4 MB, L2-resident) read DIRECT global->reg as MFMA fragments
//    (8 contiguous k-elems = 1 dwordx4), double-buffered 1 step ahead; LDS
//    holds A ONLY: [c][r] chunk-major -> conflict-free reads, no swizzle
//  - BM=256 x BN=128, 4 waves, 3 LDS slots x 16KB (48KB) -> 2 blocks/CU
//  - per K-step(32): issue B(t+1)[4] + stage slot t+2 [4 gload_lds];
//    one vmcnt(8)+barrier per step (S(t+1) drained, B(t+1)+S(t+2) in flight)
//  - grid 2304 = 8 XCD x 16 bm x 18 (r,bn), bnr fastest (A panel L2-hot)

#define DIM   768
#define NREL  3

typedef __bf16 bf16x8 __attribute__((ext_vector_type(8)));
typedef float  f32x4  __attribute__((ext_vector_type(4)));
typedef float  f32x16 __attribute__((ext_vector_type(16)));
typedef unsigned short us4 __attribute__((ext_vector_type(4)));
typedef unsigned short us8 __attribute__((ext_vector_type(8)));

// ---------------- helpers ----------------
__device__ __forceinline__ float bfs(unsigned short u){
  union { unsigned u; float f; } v; v.u = ((unsigned)u) << 16; return v.f;
}
__device__ __forceinline__ float bfl(unsigned x){
  union { unsigned u; float f; } v; v.u = x << 16; return v.f;
}
__device__ __forceinline__ float bfh(unsigned x){
  union { unsigned u; float f; } v; v.u = x & 0xffff0000u; return v.f;
}
__device__ __forceinline__ unsigned short f2bf(float f){   // RNE
  union { float f; unsigned u; } v; v.f = f;
  unsigned r = v.u + 0x7fffu + ((v.u >> 16) & 1u);
  return (unsigned short)(r >> 16);
}
__device__ __forceinline__ unsigned pck(float a, float b){
  return (unsigned)f2bf(a) | ((unsigned)f2bf(b) << 16);
}
__device__ __forceinline__ float ldf(const void* p, size_t i, int is32){
  return is32 ? ((const float*)p)[i] : bfs(((const unsigned short*)p)[i]);
}
__device__ __forceinline__ int ldi(const void* p, size_t i, int is64){
  return is64 ? ((const int*)p)[2 * i] : ((const int*)p)[i];
}

typedef __attribute__((address_space(1))) void gvoid_t;
typedef __attribute__((address_space(3))) void lvoid_t;
__device__ __forceinline__ void gload16(const void* g, void* l){
  __builtin_amdgcn_global_load_lds((gvoid_t*)g, (lvoid_t*)l, 16, 0, 0);
}

template<int H>
__device__ __forceinline__ float sel(const float (&a)[H], int h){
  float v = a[0];
#pragma unroll
  for (int i = 1; i < H; ++i) v = (h == i) ? a[i] : v;
  return v;
}

// ---------------- dtype detection ----------------
__global__ void detect_kernel(const unsigned short* __restrict__ xu,
                              const unsigned* __restrict__ eiu,
                              const unsigned* __restrict__ etyu,
                              int* __restrict__ flags){
  __shared__ int s_weird, s_ei, s_ety;
  int t = threadIdx.x;
  if (t == 0){ s_weird = 0; s_ei = 0; s_ety = 0; }
  __syncthreads();
  unsigned short u = xu[2 * t];
  int ex = (u >> 7) & 0xff;
  if (ex >= 0xF0 || ex <= 0x40) atomicAdd(&s_weird, 1);
  if (t < 128){
    if (eiu[2 * t + 1]  != 0) atomicAdd(&s_ei, 1);
    if (etyu[2 * t + 1] != 0) atomicAdd(&s_ety, 1);
  }
  __syncthreads();
  if (t == 0){
    flags[0] = (s_weird > 16) ? 1 : 0;
    flags[1] = (s_ei  == 0) ? 1 : 0;
    flags[2] = (s_ety == 0) ? 1 : 0;
  }
}

// ---------------- x -> internal bf16 ----------------
__global__ void convert_x(const void* __restrict__ xin, unsigned short* __restrict__ xb,
                          const int* __restrict__ flags, int n4){
  int i = blockIdx.x * blockDim.x + threadIdx.x;
  if (i >= n4) return;
  if (flags[0]){
    float4 v = ((const float4*)xin)[i];
    us4 o; o.x = f2bf(v.x); o.y = f2bf(v.y); o.z = f2bf(v.z); o.w = f2bf(v.w);
    ((us4*)xb)[i] = o;
  } else {
    ((us4*)xb)[i] = ((const us4*)xin)[i];
  }
}

// ---------------- CSR build ----------------
__global__ void hist_kernel(const void* __restrict__ ei, int* __restrict__ counts,
                            const int* __restrict__ flags, int E){
  int e = blockIdx.x * blockDim.x + threadIdx.x;
  if (e < E) atomicAdd(&counts[ldi(ei, (size_t)E + e, flags[1])], 1);
}

__global__ void scan_kernel(const int* __restrict__ counts, int* __restrict__ offs,
                            int* __restrict__ cursor, int n){
  __shared__ int s[1024];
  int tid = threadIdx.x;
  int base = tid * 32;
  int loc[32];
  int run = 0;
#pragma unroll
  for (int i = 0; i < 32; ++i){ loc[i] = run; run += counts[base + i]; }
  s[tid] = run;
  __syncthreads();
  for (int off = 1; off < 1024; off <<= 1){
    int add = (tid >= off) ? s[tid - off] : 0;
    __syncthreads();
    s[tid] += add;
    __syncthreads();
  }
  int ex = (tid == 0) ? 0 : s[tid - 1];
#pragma unroll
  for (int i = 0; i < 32; ++i){
    int o = ex + loc[i];
    offs[base + i]   = o;
    cursor[base + i] = o;
  }
  if (tid == 1023) offs[n] = s[1023];
}

__global__ void scatter_kernel(const void* __restrict__ ei, const void* __restrict__ ety,
                               int* __restrict__ cursor, int* __restrict__ payload,
                               const int* __restrict__ flags, int E){
  int e = blockIdx.x * blockDim.x + threadIdx.x;
  if (e < E){
    int dst = ldi(ei, (size_t)E + e, flags[1]);
    int src = ldi(ei, (size_t)e,     flags[1]);
    int et  = ldi(ety, (size_t)e,    flags[2]);
    int pos = atomicAdd(&cursor[dst], 1);
    payload[pos] = (et << 16) | src;
  }
}

// ---------------- W transpose+convert ----------------
__global__ void transpose_w(const void* __restrict__ W, unsigned short* __restrict__ Wt,
                            const int* __restrict__ flags){
  __shared__ unsigned short t[32][33];
  int is32 = flags[0];
  int r = blockIdx.z;
  size_t Wb = (size_t)r * DIM * DIM;
  unsigned short* Wd = Wt + (size_t)r * DIM * DIM;
  int tx = threadIdx.x, ty = threadIdx.y;
  int x  = blockIdx.x * 32 + tx;
  int y0 = blockIdx.y * 32;
#pragma unroll
  for (int i = 0; i < 32; i += 8)
    t[ty + i][tx] = f2bf(ldf(W, Wb + (size_t)(y0 + ty + i) * DIM + x, is32));
  __syncthreads();
  int x2 = blockIdx.y * 32 + tx;
  int y2 = blockIdx.x * 32;
#pragma unroll
  for (int i = 0; i < 32; i += 8) Wd[(size_t)(y2 + ty + i) * DIM + x2] = t[tx][ty + i];
}

// ---------------- Wqkb[d][32] (bf16) = [W@q | W@k] per relation ----------------
// col = r*8 + isK*4 + h  (cols 24..31 pad; zeroed by memset before launch)
template<int H>
__global__ void wqk_kernel(const void* __restrict__ W,
                           const void* __restrict__ q, const void* __restrict__ k,
                           unsigned short* __restrict__ Wqkb,
                           const int* __restrict__ flags){
  int is32 = flags[0];
  int wid  = (blockIdx.x * blockDim.x + threadIdx.x) >> 6;
  int lane = threadIdx.x & 63;
  int r = wid / DIM, d = wid % DIM;
  size_t Wrow = ((size_t)r * DIM + d) * DIM;
  float aq[H], ak[H];
#pragma unroll
  for (int h = 0; h < H; ++h){ aq[h] = 0.f; ak[h] = 0.f; }
#pragma unroll
  for (int j = 0; j < 12; ++j){
    int f = j * 64 + lane;
    float wv = ldf(W, Wrow + f, is32);
#pragma unroll
    for (int h = 0; h < H; ++h){
      aq[h] += wv * ldf(q, (size_t)f * H + h, is32);
      ak[h] += wv * ldf(k, (size_t)f * H + h, is32);
    }
  }
#pragma unroll
  for (int h = 0; h < H; ++h){
    for (int off = 32; off; off >>= 1){
      aq[h] += __shfl_xor(aq[h], off);
      ak[h] += __shfl_xor(ak[h], off);
    }
  }
  if (lane == 0){
#pragma unroll
    for (int h = 0; h < H; ++h){
      Wqkb[(size_t)d * 32 + r * 8 + h]     = f2bf(aq[h]);
      Wqkb[(size_t)d * 32 + r * 8 + 4 + h] = f2bf(ak[h]);
    }
  }
}

// ---------------- pack Wqkb into MFMA B-fragment order ----------------
// Bpk[t][nt][lane] = 8 bf16: Wqkb[t*32 + (lane>>4)*8 + j][nt*16 + (lane&15)]
__global__ void pack_b(const unsigned short* __restrict__ Wqkb, unsigned short* __restrict__ Bpk){
  int i = blockIdx.x * 256 + threadIdx.x;   // 24*2*64 = 3072
  if (i >= 3072) return;
  int lane = i & 63, nt = (i >> 6) & 1, t = i >> 7;
  int kb = t * 32 + (lane >> 4) * 8;
  int col = nt * 16 + (lane & 15);
  us8 v;
#pragma unroll
  for (int j = 0; j < 8; ++j) v[j] = Wqkb[(size_t)(kb + j) * 32 + col];
  ((us8*)Bpk)[i] = v;
}

// ---------------- qn/kn via skinny MFMA: [N,768]@[768,32] ----------------
// output layout qn[r][n][4], kn[r][n][4] fp32 (H=4 uses all, H=1 uses h=0)
__global__ void __launch_bounds__(256)
qnkn_mfma(const unsigned short* __restrict__ X, const unsigned short* __restrict__ Bpk,
          float* __restrict__ qn, float* __restrict__ kn, int nN){
  int wv = threadIdx.x >> 6, lane = threadIdx.x & 63;
  int row0 = (blockIdx.x * 4 + wv) * 16;
  int ar = lane & 15, quad = lane >> 4;
  const unsigned short* Arow = X + (size_t)(row0 + ar) * DIM + quad * 8;
  const bf16x8* Bp = (const bf16x8*)Bpk;
  f32x4 acc0 = {0.f,0.f,0.f,0.f}, acc1 = {0.f,0.f,0.f,0.f};
#pragma unroll
  for (int t = 0; t < 24; ++t){
    bf16x8 a  = *(const bf16x8*)(Arow + t * 32);
    bf16x8 b0 = Bp[(t * 2 + 0) * 64 + lane];
    bf16x8 b1 = Bp[(t * 2 + 1) * 64 + lane];
    acc0 = __builtin_amdgcn_mfma_f32_16x16x32_bf16(a, b0, acc0, 0, 0, 0);
    acc1 = __builtin_amdgcn_mfma_f32_16x16x32_bf16(a, b1, acc1, 0, 0, 0);
  }
#pragma unroll
  for (int nt = 0; nt < 2; ++nt){
    int col = nt * 16 + (lane & 15);
    if (col < 24){
      int r = col >> 3, isK = (col >> 2) & 1, h = col & 3;
      float* bp = isK ? kn : qn;
      f32x4 a = nt ? acc1 : acc0;
#pragma unroll
      for (int j = 0; j < 4; ++j){
        int row = row0 + quad * 4 + j;
        bp[((size_t)r * nN + row) * 4 + h] = a[j];
      }
    }
  }
}

// ---------------- MFMA GEMM: C[r] = A @ W[r], 32x32x16, B-direct, A-only LDS --
// 4 waves (2x2), wave tile 128x64 = 4x2 tiles of 32x32. A frag: row=lane&31,
// k=(lane>>5)*8+j (analogy of verified 16x16x32 layout). C/D: col=lane&31,
// row=(reg&3)+8*(reg>>2)+4*(lane>>5)  [m74/m101].
// LDS A slot layout: [c=0..3][r=0..255] 16B chunks; chunk c = k-elems c*8..+8.
// Frag reads are two contiguous 512B half-wave reads -> conflict-free.
#define PREFB(PAR, T1) {                                                      \
  Bq[PAR][0][0] = *(const bf16x8*)(gB0 + (T1) * 32);                          \
  Bq[PAR][0][1] = *(const bf16x8*)(gB0 + (T1) * 32 + 16);                     \
  Bq[PAR][1][0] = *(const bf16x8*)(gB1 + (T1) * 32);                          \
  Bq[PAR][1][1] = *(const bf16x8*)(gB1 + (T1) * 32 + 16);                     \
}
#define STAGEA(SL2, T2) {                                                     \
  gload16(gA + (size_t)  0 * DIM + (T2) * 32, &lds[(SL2)*16384 + dstbase]);        \
  gload16(gA + (size_t) 64 * DIM + (T2) * 32, &lds[(SL2)*16384 + dstbase + 1024]); \
  gload16(gA + (size_t)128 * DIM + (T2) * 32, &lds[(SL2)*16384 + dstbase + 2048]); \
  gload16(gA + (size_t)192 * DIM + (T2) * 32, &lds[(SL2)*16384 + dstbase + 3072]); \
}
#define MMQ(SL, PAR) {                                                        \
  bf16x8 a00 = *(const bf16x8*)&lds[(SL)*16384 + abase +    0];               \
  bf16x8 a10 = *(const bf16x8*)&lds[(SL)*16384 + abase +  512];               \
  bf16x8 a20 = *(const bf16x8*)&lds[(SL)*16384 + abase + 1024];               \
  bf16x8 a30 = *(const bf16x8*)&lds[(SL)*16384 + abase + 1536];               \
  bf16x8 a01 = *(const bf16x8*)&lds[(SL)*16384 + 8192 + abase +    0];        \
  bf16x8 a11 = *(const bf16x8*)&lds[(SL)*16384 + 8192 + abase +  512];        \
  bf16x8 a21 = *(const bf16x8*)&lds[(SL)*16384 + 8192 + abase + 1024];        \
  bf16x8 a31 = *(const bf16x8*)&lds[(SL)*16384 + 8192 + abase + 1536];        \
  __builtin_amdgcn_s_setprio(1);                                              \
  acc[0][0] = __builtin_amdgcn_mfma_f32_32x32x16_bf16(a00, Bq[PAR][0][0], acc[0][0], 0, 0, 0); \
  acc[0][0] = __builtin_amdgcn_mfma_f32_32x32x16_bf16(a01, Bq[PAR][0][1], acc[0][0], 0, 0, 0); \
  acc[0][1] = __builtin_amdgcn_mfma_f32_32x32x16_bf16(a00, Bq[PAR][1][0], acc[0][1], 0, 0, 0); \
  acc[0][1] = __builtin_amdgcn_mfma_f32_32x32x16_bf16(a01, Bq[PAR][1][1], acc[0][1], 0, 0, 0); \
  acc[1][0] = __builtin_amdgcn_mfma_f32_32x32x16_bf16(a10, Bq[PAR][0][0], acc[1][0], 0, 0, 0); \
  acc[1][0] = __builtin_amdgcn_mfma_f32_32x32x16_bf16(a11, Bq[PAR][0][1], acc[1][0], 0, 0, 0); \
  acc[1][1] = __builtin_amdgcn_mfma_f32_32x32x16_bf16(a10, Bq[PAR][1][0], acc[1][1], 0, 0, 0); \
  acc[1][1] = __builtin_amdgcn_mfma_f32_32x32x16_bf16(a11, Bq[PAR][1][1], acc[1][1], 0, 0, 0); \
  acc[2][0] = __builtin_amdgcn_mfma_f32_32x32x16_bf16(a20, Bq[PAR][0][0], acc[2][0], 0, 0, 0); \
  acc[2][0] = __builtin_amdgcn_mfma_f32_32x32x16_bf16(a21, Bq[PAR][0][1], acc[2][0], 0, 0, 0); \
  acc[2][1] = __builtin_amdgcn_mfma_f32_32x32x16_bf16(a20, Bq[PAR][1][0], acc[2][1], 0, 0, 0); \
  acc[2][1] = __builtin_amdgcn_mfma_f32_32x32x16_bf16(a21, Bq[PAR][1][1], acc[2][1], 0, 0, 0); \
  acc[3][0] = __builtin_amdgcn_mfma_f32_32x32x16_bf16(a30, Bq[PAR][0][0], acc[3][0], 0, 0, 0); \
  acc[3][0] = __builtin_amdgcn_mfma_f32_32x32x16_bf16(a31, Bq[PAR][0][1], acc[3][0], 0, 0, 0); \
  acc[3][1] = __builtin_amdgcn_mfma_f32_32x32x16_bf16(a30, Bq[PAR][1][0], acc[3][1], 0, 0, 0); \
  acc[3][1] = __builtin_amdgcn_mfma_f32_32x32x16_bf16(a31, Bq[PAR][1][1], acc[3][1], 0, 0, 0); \
  __builtin_amdgcn_s_setprio(0);                                              \
}
#define STEPF(T, SL, PAR) { PREFB((PAR)^1, (T)+1); STAGEA(((SL)+2)%3, (T)+2); MMQ(SL, PAR); }
#define W8 { asm volatile("s_waitcnt vmcnt(8)" ::: "memory"); __builtin_amdgcn_s_barrier(); }
#define W4 { asm volatile("s_waitcnt vmcnt(4)" ::: "memory"); __builtin_amdgcn_s_barrier(); }

__global__ void __launch_bounds__(256, 2)
gemm_bf16(const unsigned short* __restrict__ A,
          const unsigned short* __restrict__ Bt,
          unsigned short* __restrict__ C, int M){
  __shared__ __align__(16) unsigned char lds[49152];   // 3 slots x 16KB (A only)
  const int K = DIM;
  int i = blockIdx.x;
  int xcd = i & 7, s = i >> 3;            // s in 0..287
  int bm  = xcd * 16 + s / 18;            // 0..127 (M/256 tiles)
  int bnr = s % 18;
  int rrel = bnr / 6, bn = bnr % 6;       // 6 N-tiles of 128 per relation
  int tid = threadIdx.x;
  int w = tid >> 6, lane = tid & 63;
  int wr = w >> 1, wc = w & 1;            // 2x2 wave grid, wave tile 128x64
  int lo = lane & 31, hi = lane >> 5;

  // A frag read: addr = SL*16384 + (kk*2+hi)*4096 + (wr*128 + mi*32 + lo)*16
  int abase = hi * 4096 + (wr * 128 + lo) * 16;
  // staging: wave w stages chunk c=w (k-elems w*8..w*8+8), rows it*64+lane
  const unsigned short* gA = A + ((size_t)bm * 256 + lane) * K + w * 8;
  int dstbase = w * 4096;
  // B direct-from-global fragments: row = rrel*768 + bn*128 + wc*64 + ni*32 + lo
  const unsigned short* gB0 = Bt + ((size_t)rrel * DIM + bn * 128 + wc * 64 + lo) * K + hi * 8;
  const unsigned short* gB1 = gB0 + (size_t)32 * K;

  f32x16 acc[4][2];
  f32x16 zz = {0.f,0.f,0.f,0.f,0.f,0.f,0.f,0.f,0.f,0.f,0.f,0.f,0.f,0.f,0.f,0.f};
#pragma unroll
  for (int a = 0; a < 4; ++a){ acc[a][0] = zz; acc[a][1] = zz; }
  bf16x8 Bq[2][2][2];   // [parity][ni][kk] -- all indices compile-time

  // prologue: stage slots 0,1; load B(0); wait slot0 (S1+B0 stay in flight)
  STAGEA(0, 0); STAGEA(1, 1);
  PREFB(0, 0);
  W8;

#pragma unroll 1
  for (int t0 = 0; t0 < 18; t0 += 6){     // K-steps 0..17 (slot t%3, par t&1)
    STEPF(t0 + 0, 0, 0); W8;
    STEPF(t0 + 1, 1, 1); W8;
    STEPF(t0 + 2, 2, 0); W8;
    STEPF(t0 + 3, 0, 1); W8;
    STEPF(t0 + 4, 1, 0); W8;
    STEPF(t0 + 5, 2, 1); W8;
  }
  STEPF(18, 0, 0); W8;
  STEPF(19, 1, 1); W8;
  STEPF(20, 2, 0); W8;
  STEPF(21, 0, 1); W8;                    // stages slot2 (t=23), loads B22
  PREFB(1, 23); MMQ(1, 0);                // t=22: B23 only, no staging
  W4;                                     // drain S23, B23 stays in flight
  MMQ(2, 1);                              // t=23

  unsigned short* Cg = C + ((size_t)rrel * M + (size_t)bm * 256) * DIM + bn * 128;
#pragma unroll
  for (int mi = 0; mi < 4; ++mi)
#pragma unroll
    for (int ni = 0; ni < 2; ++ni)
#pragma unroll
      for (int rg = 0; rg < 4; ++rg)
#pragma unroll
        for (int j = 0; j < 4; ++j){
          int row = wr * 128 + mi * 32 + rg * 8 + hi * 4 + j;
          int col = wc * 64 + ni * 32 + lo;
          Cg[(size_t)row * DIM + col] = f2bf(acc[mi][ni][rg * 4 + j]);
        }
}

// ---------------- per-node attention + aggregation (one wave per node) ----------------
// Per-wave LDS for chunk payload/weights (no inner-loop shuffles); gathers
// batched 4-wide for MLP (12 independent loads in flight).
template<int H, bool ELU, bool OUT32>
__global__ void __launch_bounds__(256)
agg_kernel(const unsigned short* __restrict__ xr,
           const float* __restrict__ qn, const float* __restrict__ kn,
           const int* __restrict__ offs, const int* __restrict__ payload,
           const void* __restrict__ bias,
           void* __restrict__ outp,
           const int* __restrict__ flags, int nN, int E){
  const int WH = (H == 4) ? 4 : 1;
  __shared__ int   pay_s[4][64];
  __shared__ float w_s[4][64 * WH];
  int is32 = flags[0];
  int wv   = threadIdx.x >> 6;
  int lane = threadIdx.x & 63;
  int n = blockIdx.x * 4 + wv;
  int rs = offs[n], re = offs[n + 1];
  rs = max(rs, 0); re = min(re, E);
  const int myh = (H == 1) ? 0 : (lane >> 4);   // OUTC=192: lane*12/192 = lane/16

  float m_run[H], z_run[H], acc[12];
#pragma unroll
  for (int h = 0; h < H; ++h){ m_run[h] = -__builtin_inff(); z_run[h] = 0.f; }
#pragma unroll
  for (int i = 0; i < 12; ++i) acc[i] = 0.f;

  for (int base = rs; base < re; base += 64){
    int dc = min(64, re - base);
    int pay = 0;
    float al[H];
#pragma unroll
    for (int h = 0; h < H; ++h) al[h] = -__builtin_inff();
    if (lane < dc){
      pay = payload[base + lane];
      int et = pay >> 16, src = pay & 0xffff;
      if (H == 4){
        f32x4 qv = *(const f32x4*)(qn + ((size_t)et * nN + n)   * 4);
        f32x4 kv = *(const f32x4*)(kn + ((size_t)et * nN + src) * 4);
#pragma unroll
        for (int h = 0; h < H; ++h){
          float a = qv[h & 3] + kv[h & 3];
          al[h] = (a > 0.f) ? a : 0.2f * a;
        }
      } else {
        float a = qn[((size_t)et * nN + n) * 4] + kn[((size_t)et * nN + src) * 4];
        al[0] = (a > 0.f) ? a : 0.2f * a;
      }
    }
    // online-softmax chunk update
    float scs[H], wgt[H];
#pragma unroll
    for (int h = 0; h < H; ++h){
      float v = al[h];
      for (int off = 32; off; off >>= 1) v = fmaxf(v, __shfl_xor(v, off));
      float nm = fmaxf(m_run[h], v);
      scs[h] = (m_run[h] == -__builtin_inff()) ? 0.f : expf(m_run[h] - nm);
      m_run[h] = nm;
      wgt[h] = (lane < dc) ? expf(al[h] - nm) : 0.f;
      float s = wgt[h];
      for (int off = 32; off; off >>= 1) s += __shfl_xor(s, off);
      z_run[h] = z_run[h] * scs[h] + s;
    }
    float msc = sel<H>(scs, myh);
#pragma unroll
    for (int i = 0; i < 12; ++i) acc[i] *= msc;

    // stash chunk data in per-wave LDS (same-wave DS ops are in-order)
    if (lane < dc){
      pay_s[wv][lane] = pay;
#pragma unroll
      for (int h = 0; h < WH; ++h) w_s[wv][lane * WH + h] = wgt[h];
    }

    // batched gather-accumulate: 4 edges -> 12 loads in flight
    for (int j0 = 0; j0 < dc; j0 += 4){
      uint2 c[4][3];
      float w4[4];
#pragma unroll
      for (int u = 0; u < 4; ++u){
        int jc = j0 + u;
        int ok = jc < dc;
        int jl = ok ? jc : j0;
        int pj = pay_s[wv][jl];
        float ww = w_s[wv][jl * WH + ((H == 1) ? 0 : myh)];
        w4[u] = ok ? ww : 0.f;
        int et = pj >> 16, src = pj & 0xffff;
        const uint2* rp = (const uint2*)(xr + ((size_t)et * nN + src) * DIM + lane * 12);
        c[u][0] = rp[0]; c[u][1] = rp[1]; c[u][2] = rp[2];
      }
#pragma unroll
      for (int u = 0; u < 4; ++u){
        float wj = w4[u];
        acc[0]  += wj * bfl(c[u][0].x); acc[1]  += wj * bfh(c[u][0].x);
        acc[2]  += wj * bfl(c[u][0].y); acc[3]  += wj * bfh(c[u][0].y);
        acc[4]  += wj * bfl(c[u][1].x); acc[5]  += wj * bfh(c[u][1].x);
        acc[6]  += wj * bfl(c[u][1].y); acc[7]  += wj * bfh(c[u][1].y);
        acc[8]  += wj * bfl(c[u][2].x); acc[9]  += wj * bfh(c[u][2].x);
        acc[10] += wj * bfl(c[u][2].y); acc[11] += wj * bfh(c[u][2].y);
      }
    }
  }

  float inv = 1.0f / (sel<H>(z_run, myh) + 1e-16f);
  float o[12];
#pragma unroll
  for (int i = 0; i < 12; ++i){
    float v = acc[i] * inv + ldf(bias, (size_t)lane * 12 + i, is32);
    if (ELU) v = (v > 0.f) ? v : (expf(v) - 1.f);
    o[i] = v;
  }
  if (OUT32 && is32){
    float* op = (float*)outp + (size_t)n * DIM + lane * 12;
    float4 f0 = {o[0], o[1], o[2],  o[3]};
    float4 f1 = {o[4], o[5], o[6],  o[7]};
    float4 f2 = {o[8], o[9], o[10], o[11]};
    ((float4*)op)[0] = f0; ((float4*)op)[1] = f1; ((float4*)op)[2] = f2;
  } else {
    uint2* op = (uint2*)((unsigned short*)outp + (size_t)n * DIM + lane * 12);
    uint2 s0, s1, s2;
    s0.x = pck(o[0], o[1]);  s0.y = pck(o[2], o[3]);
    s1.x = pck(o[4], o[5]);  s1.y = pck(o[6], o[7]);
    s2.x = pck(o[8], o[9]);  s2.y = pck(o[10], o[11]);
    op[0] = s0; op[1] = s1; op[2] = s2;
  }
}

// ---------------- launcher ----------------
extern "C" void kernel_launch(void* const* d_in, const int* in_sizes, int n_in,
                              void* d_out, int out_size, void* d_ws, size_t ws_size,
                              hipStream_t stream){
  const void* x   = d_in[0];
  const void* ei  = d_in[1];
  const void* ety = d_in[2];
  const void* W1  = d_in[3];
  const void* q1  = d_in[4];
  const void* k1  = d_in[5];
  const void* b1  = d_in[6];
  const void* W2  = d_in[7];
  const void* q2  = d_in[8];
  const void* k2  = d_in[9];
  const void* b2  = d_in[10];

  int nN = in_sizes[0] / DIM;   // 32768
  int E  = in_sizes[2];         // 160000

  char* ws = (char*)d_ws;
  size_t off = 0;
  auto alloc = [&](size_t bytes) -> void* {
    void* p = ws + off;
    off += (bytes + 255) & ~(size_t)255;
    return p;
  };
  unsigned short* xr   = (unsigned short*)alloc((size_t)NREL * nN * DIM * 2);
  unsigned short* xb   = (unsigned short*)alloc((size_t)nN * DIM * 2);
  unsigned short* h    = (unsigned short*)alloc((size_t)nN * DIM * 2);
  unsigned short* Wt   = (unsigned short*)alloc((size_t)NREL * DIM * DIM * 2);
  unsigned short* Wqkb = (unsigned short*)alloc((size_t)DIM * 32 * 2);
  unsigned short* Bpk  = (unsigned short*)alloc((size_t)3072 * 16);
  float* qn  = (float*)alloc((size_t)NREL * nN * 4 * 4);
  float* kn  = (float*)alloc((size_t)NREL * nN * 4 * 4);
  int* offs    = (int*)alloc((size_t)(nN + 1) * 4);
  int* cursor  = (int*)alloc((size_t)nN * 4);
  int* counts  = (int*)alloc((size_t)nN * 4);
  int* payload = (int*)alloc((size_t)E * 4);
  int* flags   = (int*)alloc(16);

  detect_kernel<<<1, 256, 0, stream>>>((const unsigned short*)x, (const unsigned*)ei,
                                       (const unsigned*)ety, flags);
  convert_x<<<(nN * DIM / 4 + 255) / 256, 256, 0, stream>>>(x, xb, flags, nN * DIM / 4);

  hipMemsetAsync(counts, 0, (size_t)nN * 4, stream);
  hist_kernel<<<(E + 255) / 256, 256, 0, stream>>>(ei, counts, flags, E);
  scan_kernel<<<1, 1024, 0, stream>>>(counts, offs, cursor, nN);
  scatter_kernel<<<(E + 255) / 256, 256, 0, stream>>>(ei, ety, cursor, payload, flags, E);

  dim3 tg(DIM / 32, DIM / 32, NREL), tb(32, 8);
  int gemm_blocks = 8 * (16 * 18);   // 2304: 128 m-tiles x 18 (r,bn)

  // ---- layer 1 (H=4, ELU) ----
  transpose_w<<<tg, tb, 0, stream>>>(W1, Wt, flags);
  hipMemsetAsync(Wqkb, 0, (size_t)DIM * 32 * 2, stream);
  wqk_kernel<4><<<(NREL * DIM) / 4, 256, 0, stream>>>(W1, q1, k1, Wqkb, flags);
  pack_b<<<12, 256, 0, stream>>>(Wqkb, Bpk);
  qnkn_mfma<<<nN / 64, 256, 0, stream>>>(xb, Bpk, qn, kn, nN);
  gemm_bf16<<<gemm_blocks, 256, 0, stream>>>(xb, Wt, xr, nN);
  agg_kernel<4, true, false><<<nN / 4, 256, 0, stream>>>(xr, qn, kn, offs, payload, b1, h,
                                                         flags, nN, E);

  // ---- layer 2 (H=1, no activation) ----
  transpose_w<<<tg, tb, 0, stream>>>(W2, Wt, flags);
  hipMemsetAsync(Wqkb, 0, (size_t)DIM * 32 * 2, stream);
  wqk_kernel<1><<<(NREL * DIM) / 4, 256, 0, stream>>>(W2, q2, k2, Wqkb, flags);
  pack_b<<<12, 256, 0, stream>>>(Wqkb, Bpk);
  qnkn_mfma<<<nN / 64, 256, 0, stream>>>(h, Bpk, qn, kn, nN);
  gemm_bf16<<<gemm_blocks, 256, 0, stream>>>(h, Wt, xr, nN);
  agg_kernel<1, false, true><<<nN / 4, 256, 0, stream>>>(xr, qn, kn, offs, payload, b2,
                                                         d_out, flags, nN, E);
}

// Round 4
// 661.329 us; speedup vs baseline: 1.2807x; 1.2807x over previous
//
#include <hip/hip_runtime.h>

// RGAT encoder, 2 layers. N=32768, E=160000, DIM=768, R=3, heads 4 then 1.
// Round 8 (from 653 us; R2's 847 us B-direct experiment reverted): R2's
// global B-fragment gather (32 rows x 16B, stride 1536B) was request-rate
// bound (MfmaUtil 20, VALU 9, HBM 16) -- but it VERIFIED the 32x32x16
// fragment layouts. Corrected machine model: dense peak = 4096 FLOP/cyc/CU
// (one matrix pipe per CU); R1's 39% came from too little MFMA work per
// sync point (16 x 16x16 MFMA per wave-step). This round:
//  - R1's proven 3-slot counted-vmcnt pipeline + XOR row-pair LDS staging
//    (coalesced gload_lds, 0 conflicts) for BOTH A and B
//  - 32x32x16 MFMA (verified by R2), wave tile 128x64, 4 waves, BM=256xBN=128
//  - per K-step(32): 6 gload_lds + 12 ds_read_b128 + 16 MFMA (128 matrix-cyc)
//    against ONE vmcnt(6) + ONE barrier; 2.6x more work/sync than R1
//  - 3 slots x 24KB = 72KB -> 2 blocks/CU (launch_bounds(256,2))
//  - grid 2304 = 8 XCD x 16 bm x 18 (r,bn), bnr fastest (A panel L2-hot)

#define DIM   768
#define NREL  3

typedef __bf16 bf16x8 __attribute__((ext_vector_type(8)));
typedef float  f32x4  __attribute__((ext_vector_type(4)));
typedef float  f32x16 __attribute__((ext_vector_type(16)));
typedef unsigned short us4 __attribute__((ext_vector_type(4)));
typedef unsigned short us8 __attribute__((ext_vector_type(8)));

// ---------------- helpers ----------------
__device__ __forceinline__ float bfs(unsigned short u){
  union { unsigned u; float f; } v; v.u = ((unsigned)u) << 16; return v.f;
}
__device__ __forceinline__ float bfl(unsigned x){
  union { unsigned u; float f; } v; v.u = x << 16; return v.f;
}
__device__ __forceinline__ float bfh(unsigned x){
  union { unsigned u; float f; } v; v.u = x & 0xffff0000u; return v.f;
}
__device__ __forceinline__ unsigned short f2bf(float f){   // RNE
  union { float f; unsigned u; } v; v.f = f;
  unsigned r = v.u + 0x7fffu + ((v.u >> 16) & 1u);
  return (unsigned short)(r >> 16);
}
__device__ __forceinline__ unsigned pck(float a, float b){
  return (unsigned)f2bf(a) | ((unsigned)f2bf(b) << 16);
}
__device__ __forceinline__ float ldf(const void* p, size_t i, int is32){
  return is32 ? ((const float*)p)[i] : bfs(((const unsigned short*)p)[i]);
}
__device__ __forceinline__ int ldi(const void* p, size_t i, int is64){
  return is64 ? ((const int*)p)[2 * i] : ((const int*)p)[i];
}

typedef __attribute__((address_space(1))) void gvoid_t;
typedef __attribute__((address_space(3))) void lvoid_t;
__device__ __forceinline__ void gload16(const void* g, void* l){
  __builtin_amdgcn_global_load_lds((gvoid_t*)g, (lvoid_t*)l, 16, 0, 0);
}

template<int H>
__device__ __forceinline__ float sel(const float (&a)[H], int h){
  float v = a[0];
#pragma unroll
  for (int i = 1; i < H; ++i) v = (h == i) ? a[i] : v;
  return v;
}

// ---------------- dtype detection ----------------
__global__ void detect_kernel(const unsigned short* __restrict__ xu,
                              const unsigned* __restrict__ eiu,
                              const unsigned* __restrict__ etyu,
                              int* __restrict__ flags){
  __shared__ int s_weird, s_ei, s_ety;
  int t = threadIdx.x;
  if (t == 0){ s_weird = 0; s_ei = 0; s_ety = 0; }
  __syncthreads();
  unsigned short u = xu[2 * t];
  int ex = (u >> 7) & 0xff;
  if (ex >= 0xF0 || ex <= 0x40) atomicAdd(&s_weird, 1);
  if (t < 128){
    if (eiu[2 * t + 1]  != 0) atomicAdd(&s_ei, 1);
    if (etyu[2 * t + 1] != 0) atomicAdd(&s_ety, 1);
  }
  __syncthreads();
  if (t == 0){
    flags[0] = (s_weird > 16) ? 1 : 0;
    flags[1] = (s_ei  == 0) ? 1 : 0;
    flags[2] = (s_ety == 0) ? 1 : 0;
  }
}

// ---------------- x -> internal bf16 ----------------
__global__ void convert_x(const void* __restrict__ xin, unsigned short* __restrict__ xb,
                          const int* __restrict__ flags, int n4){
  int i = blockIdx.x * blockDim.x + threadIdx.x;
  if (i >= n4) return;
  if (flags[0]){
    float4 v = ((const float4*)xin)[i];
    us4 o; o.x = f2bf(v.x); o.y = f2bf(v.y); o.z = f2bf(v.z); o.w = f2bf(v.w);
    ((us4*)xb)[i] = o;
  } else {
    ((us4*)xb)[i] = ((const us4*)xin)[i];
  }
}

// ---------------- CSR build ----------------
__global__ void hist_kernel(const void* __restrict__ ei, int* __restrict__ counts,
                            const int* __restrict__ flags, int E){
  int e = blockIdx.x * blockDim.x + threadIdx.x;
  if (e < E) atomicAdd(&counts[ldi(ei, (size_t)E + e, flags[1])], 1);
}

__global__ void scan_kernel(const int* __restrict__ counts, int* __restrict__ offs,
                            int* __restrict__ cursor, int n){
  __shared__ int s[1024];
  int tid = threadIdx.x;
  int base = tid * 32;
  int loc[32];
  int run = 0;
#pragma unroll
  for (int i = 0; i < 32; ++i){ loc[i] = run; run += counts[base + i]; }
  s[tid] = run;
  __syncthreads();
  for (int off = 1; off < 1024; off <<= 1){
    int add = (tid >= off) ? s[tid - off] : 0;
    __syncthreads();
    s[tid] += add;
    __syncthreads();
  }
  int ex = (tid == 0) ? 0 : s[tid - 1];
#pragma unroll
  for (int i = 0; i < 32; ++i){
    int o = ex + loc[i];
    offs[base + i]   = o;
    cursor[base + i] = o;
  }
  if (tid == 1023) offs[n] = s[1023];
}

__global__ void scatter_kernel(const void* __restrict__ ei, const void* __restrict__ ety,
                               int* __restrict__ cursor, int* __restrict__ payload,
                               const int* __restrict__ flags, int E){
  int e = blockIdx.x * blockDim.x + threadIdx.x;
  if (e < E){
    int dst = ldi(ei, (size_t)E + e, flags[1]);
    int src = ldi(ei, (size_t)e,     flags[1]);
    int et  = ldi(ety, (size_t)e,    flags[2]);
    int pos = atomicAdd(&cursor[dst], 1);
    payload[pos] = (et << 16) | src;
  }
}

// ---------------- W transpose+convert ----------------
__global__ void transpose_w(const void* __restrict__ W, unsigned short* __restrict__ Wt,
                            const int* __restrict__ flags){
  __shared__ unsigned short t[32][33];
  int is32 = flags[0];
  int r = blockIdx.z;
  size_t Wb = (size_t)r * DIM * DIM;
  unsigned short* Wd = Wt + (size_t)r * DIM * DIM;
  int tx = threadIdx.x, ty = threadIdx.y;
  int x  = blockIdx.x * 32 + tx;
  int y0 = blockIdx.y * 32;
#pragma unroll
  for (int i = 0; i < 32; i += 8)
    t[ty + i][tx] = f2bf(ldf(W, Wb + (size_t)(y0 + ty + i) * DIM + x, is32));
  __syncthreads();
  int x2 = blockIdx.y * 32 + tx;
  int y2 = blockIdx.x * 32;
#pragma unroll
  for (int i = 0; i < 32; i += 8) Wd[(size_t)(y2 + ty + i) * DIM + x2] = t[tx][ty + i];
}

// ---------------- Wqkb[d][32] (bf16) = [W@q | W@k] per relation ----------------
// col = r*8 + isK*4 + h  (cols 24..31 pad; zeroed by memset before launch)
template<int H>
__global__ void wqk_kernel(const void* __restrict__ W,
                           const void* __restrict__ q, const void* __restrict__ k,
                           unsigned short* __restrict__ Wqkb,
                           const int* __restrict__ flags){
  int is32 = flags[0];
  int wid  = (blockIdx.x * blockDim.x + threadIdx.x) >> 6;
  int lane = threadIdx.x & 63;
  int r = wid / DIM, d = wid % DIM;
  size_t Wrow = ((size_t)r * DIM + d) * DIM;
  float aq[H], ak[H];
#pragma unroll
  for (int h = 0; h < H; ++h){ aq[h] = 0.f; ak[h] = 0.f; }
#pragma unroll
  for (int j = 0; j < 12; ++j){
    int f = j * 64 + lane;
    float wv = ldf(W, Wrow + f, is32);
#pragma unroll
    for (int h = 0; h < H; ++h){
      aq[h] += wv * ldf(q, (size_t)f * H + h, is32);
      ak[h] += wv * ldf(k, (size_t)f * H + h, is32);
    }
  }
#pragma unroll
  for (int h = 0; h < H; ++h){
    for (int off = 32; off; off >>= 1){
      aq[h] += __shfl_xor(aq[h], off);
      ak[h] += __shfl_xor(ak[h], off);
    }
  }
  if (lane == 0){
#pragma unroll
    for (int h = 0; h < H; ++h){
      Wqkb[(size_t)d * 32 + r * 8 + h]     = f2bf(aq[h]);
      Wqkb[(size_t)d * 32 + r * 8 + 4 + h] = f2bf(ak[h]);
    }
  }
}

// ---------------- pack Wqkb into MFMA B-fragment order ----------------
// Bpk[t][nt][lane] = 8 bf16: Wqkb[t*32 + (lane>>4)*8 + j][nt*16 + (lane&15)]
__global__ void pack_b(const unsigned short* __restrict__ Wqkb, unsigned short* __restrict__ Bpk){
  int i = blockIdx.x * 256 + threadIdx.x;   // 24*2*64 = 3072
  if (i >= 3072) return;
  int lane = i & 63, nt = (i >> 6) & 1, t = i >> 7;
  int kb = t * 32 + (lane >> 4) * 8;
  int col = nt * 16 + (lane & 15);
  us8 v;
#pragma unroll
  for (int j = 0; j < 8; ++j) v[j] = Wqkb[(size_t)(kb + j) * 32 + col];
  ((us8*)Bpk)[i] = v;
}

// ---------------- qn/kn via skinny MFMA: [N,768]@[768,32] ----------------
// output layout qn[r][n][4], kn[r][n][4] fp32 (H=4 uses all, H=1 uses h=0)
__global__ void __launch_bounds__(256)
qnkn_mfma(const unsigned short* __restrict__ X, const unsigned short* __restrict__ Bpk,
          float* __restrict__ qn, float* __restrict__ kn, int nN){
  int wv = threadIdx.x >> 6, lane = threadIdx.x & 63;
  int row0 = (blockIdx.x * 4 + wv) * 16;
  int ar = lane & 15, quad = lane >> 4;
  const unsigned short* Arow = X + (size_t)(row0 + ar) * DIM + quad * 8;
  const bf16x8* Bp = (const bf16x8*)Bpk;
  f32x4 acc0 = {0.f,0.f,0.f,0.f}, acc1 = {0.f,0.f,0.f,0.f};
#pragma unroll
  for (int t = 0; t < 24; ++t){
    bf16x8 a  = *(const bf16x8*)(Arow + t * 32);
    bf16x8 b0 = Bp[(t * 2 + 0) * 64 + lane];
    bf16x8 b1 = Bp[(t * 2 + 1) * 64 + lane];
    acc0 = __builtin_amdgcn_mfma_f32_16x16x32_bf16(a, b0, acc0, 0, 0, 0);
    acc1 = __builtin_amdgcn_mfma_f32_16x16x32_bf16(a, b1, acc1, 0, 0, 0);
  }
#pragma unroll
  for (int nt = 0; nt < 2; ++nt){
    int col = nt * 16 + (lane & 15);
    if (col < 24){
      int r = col >> 3, isK = (col >> 2) & 1, h = col & 3;
      float* bp = isK ? kn : qn;
      f32x4 a = nt ? acc1 : acc0;
#pragma unroll
      for (int j = 0; j < 4; ++j){
        int row = row0 + quad * 4 + j;
        bp[((size_t)r * nN + row) * 4 + h] = a[j];
      }
    }
  }
}

// ---------------- MFMA GEMM: C[r]=A@W[r], 32x32x16, 256x128 tile, 3-slot pipe --
// 4 waves (2x2), wave tile 128x64 = 4x2 tiles of 32x32.
// LDS slot (24KB) = A plane 16KB (128 plane-rows x 128B) + B plane 8KB (64).
// Plane row j = global rows {2j, 2j+1} x 64B (K-32 slice); logical chunk
// sq (sq>>2 = row parity, sq&3 = 16B quarter) at phys chunk p = sq ^ (j&7).
// Frag read (32x32x16, verified R2): row=lo, k=hi*8+j; p=(rlow*4+h*2+hi)^((lo>>1)&7).
// One vmcnt(6) + one s_barrier per K-step; STAGE(t+2) issued first in step t.
#define MF(A_, B_, C_) __builtin_amdgcn_mfma_f32_32x32x16_bf16(A_, B_, C_, 0, 0, 0)

#define STAGE(SW, KW) {                                                       \
  gload16(gAa + (KW),            &lds[(SW)*24576 +         wB]);              \
  gload16(gAa +  64*DIM + (KW),  &lds[(SW)*24576 +  4096 + wB]);              \
  gload16(gAa + 128*DIM + (KW),  &lds[(SW)*24576 +  8192 + wB]);              \
  gload16(gAa + 192*DIM + (KW),  &lds[(SW)*24576 + 12288 + wB]);              \
  gload16(gBb + (KW),            &lds[(SW)*24576 + 16384 + wB]);              \
  gload16(gBb +  64*DIM + (KW),  &lds[(SW)*24576 + 20480 + wB]);              \
}

#define STEP(S, KW, DOST) {                                                   \
  if (DOST) STAGE(((S)+2)%3, KW);                                             \
  bf16x8 b00 = *(const bf16x8*)&lds[(S)*24576 + boff0];                       \
  bf16x8 b01 = *(const bf16x8*)&lds[(S)*24576 + boff1];                       \
  bf16x8 b10 = *(const bf16x8*)&lds[(S)*24576 + boff0 + 2048];                \
  bf16x8 b11 = *(const bf16x8*)&lds[(S)*24576 + boff1 + 2048];                \
  bf16x8 a00 = *(const bf16x8*)&lds[(S)*24576 + aoff0];                       \
  bf16x8 a01 = *(const bf16x8*)&lds[(S)*24576 + aoff1];                       \
  bf16x8 a10 = *(const bf16x8*)&lds[(S)*24576 + aoff0 + 2048];                \
  bf16x8 a11 = *(const bf16x8*)&lds[(S)*24576 + aoff1 + 2048];                \
  bf16x8 a20 = *(const bf16x8*)&lds[(S)*24576 + aoff0 + 4096];                \
  bf16x8 a21 = *(const bf16x8*)&lds[(S)*24576 + aoff1 + 4096];                \
  bf16x8 a30 = *(const bf16x8*)&lds[(S)*24576 + aoff0 + 6144];                \
  bf16x8 a31 = *(const bf16x8*)&lds[(S)*24576 + aoff1 + 6144];                \
  __builtin_amdgcn_s_setprio(1);                                              \
  acc[0][0] = MF(a00, b00, acc[0][0]); acc[0][1] = MF(a00, b10, acc[0][1]);   \
  acc[1][0] = MF(a10, b00, acc[1][0]); acc[1][1] = MF(a10, b10, acc[1][1]);   \
  acc[2][0] = MF(a20, b00, acc[2][0]); acc[2][1] = MF(a20, b10, acc[2][1]);   \
  acc[3][0] = MF(a30, b00, acc[3][0]); acc[3][1] = MF(a30, b10, acc[3][1]);   \
  acc[0][0] = MF(a01, b01, acc[0][0]); acc[0][1] = MF(a01, b11, acc[0][1]);   \
  acc[1][0] = MF(a11, b01, acc[1][0]); acc[1][1] = MF(a11, b11, acc[1][1]);   \
  acc[2][0] = MF(a21, b01, acc[2][0]); acc[2][1] = MF(a21, b11, acc[2][1]);   \
  acc[3][0] = MF(a31, b01, acc[3][0]); acc[3][1] = MF(a31, b11, acc[3][1]);   \
  __builtin_amdgcn_s_setprio(0);                                              \
}
#define W6 { asm volatile("s_waitcnt vmcnt(6)" ::: "memory"); __builtin_amdgcn_s_barrier(); }

__global__ void __launch_bounds__(256, 2)
gemm_bf16(const unsigned short* __restrict__ A,
          const unsigned short* __restrict__ Bt,
          unsigned short* __restrict__ C, int M){
  __shared__ __align__(16) unsigned char lds[73728];   // 3 slots x 24KB
  const int K = DIM;
  int i = blockIdx.x;
  int xcd = i & 7, s = i >> 3;            // s in 0..287
  int bm  = xcd * 16 + s / 18;            // 0..127 (M/256 tiles)
  int bnr = s % 18;
  int rrel = bnr / 6, bn = bnr % 6;       // 6 N-tiles of 128 per relation
  int tid = threadIdx.x;
  int w = tid >> 6, lane = tid & 63;
  int wr = w >> 1, wc = w & 1;            // 2x2 wave grid, wave tile 128x64
  int lo = lane & 31, hi = lane >> 5;

  // frag-read constants
  int jl   = lo >> 1, rlow = lo & 1, e7 = jl & 7;
  int p0   = (rlow * 4 + hi)     ^ e7;    // k-half h=0
  int p1   = (rlow * 4 + 2 + hi) ^ e7;    // k-half h=1
  int aoff0 = (wr * 64 + jl) * 128 + p0 * 16;
  int aoff1 = (wr * 64 + jl) * 128 + p1 * 16;
  int boff0 = 16384 + (wc * 32 + jl) * 128 + p0 * 16;
  int boff1 = 16384 + (wc * 32 + jl) * 128 + p1 * 16;

  // staging constants: thread t writes phys chunk p=t&7 of plane row (it*32+t>>3),
  // holding logical chunk sq = p ^ ((t>>3)&7)
  int sq   = (tid & 7) ^ ((tid >> 3) & 7);
  int srow = 2 * (tid >> 3) + (sq >> 2);         // 0..63
  const unsigned short* gAa = A  + ((size_t)bm * 256 + srow) * K + (sq & 3) * 8;
  const unsigned short* gBb = Bt + ((size_t)(rrel * DIM + bn * 128 + srow)) * K + (sq & 3) * 8;
  int wB = w * 1024;                             // wave-uniform LDS dest base

  f32x16 acc[4][2];
  f32x16 zz = {0.f,0.f,0.f,0.f,0.f,0.f,0.f,0.f,0.f,0.f,0.f,0.f,0.f,0.f,0.f,0.f};
#pragma unroll
  for (int a = 0; a < 4; ++a){ acc[a][0] = zz; acc[a][1] = zz; }

  // prologue: stage slots 0 (k=0) and 1 (k=32); wait slot0 (slot1 in flight)
  STAGE(0, 0); STAGE(1, 32);
  W6;

#pragma unroll 1
  for (int t7 = 0; t7 < 7; ++t7){          // K-steps 0..20 (slot = t%3)
    int kb = t7 * 96;
    STEP(0, kb + 64,  1); W6;
    STEP(1, kb + 96,  1); W6;
    STEP(2, kb + 128, 1); W6;
  }
  STEP(0, 736, 1); W6;                     // t=21, stages t=23 -> slot 2
  STEP(1, 0, 0);                           // t=22
  asm volatile("s_waitcnt vmcnt(0)" ::: "memory");
  __builtin_amdgcn_s_barrier();
  STEP(2, 0, 0);                           // t=23

  unsigned short* Cg = C + ((size_t)rrel * M + (size_t)bm * 256) * DIM + bn * 128;
#pragma unroll
  for (int mi = 0; mi < 4; ++mi)
#pragma unroll
    for (int ni = 0; ni < 2; ++ni)
#pragma unroll
      for (int rg = 0; rg < 4; ++rg)
#pragma unroll
        for (int j = 0; j < 4; ++j){
          int row = wr * 128 + mi * 32 + rg * 8 + hi * 4 + j;
          int col = wc * 64 + ni * 32 + lo;
          Cg[(size_t)row * DIM + col] = f2bf(acc[mi][ni][rg * 4 + j]);
        }
}

// ---------------- per-node attention + aggregation (one wave per node) ----------------
// Per-wave LDS for chunk payload/weights (no inner-loop shuffles); gathers
// batched 4-wide for MLP (12 independent loads in flight).
template<int H, bool ELU, bool OUT32>
__global__ void __launch_bounds__(256)
agg_kernel(const unsigned short* __restrict__ xr,
           const float* __restrict__ qn, const float* __restrict__ kn,
           const int* __restrict__ offs, const int* __restrict__ payload,
           const void* __restrict__ bias,
           void* __restrict__ outp,
           const int* __restrict__ flags, int nN, int E){
  const int WH = (H == 4) ? 4 : 1;
  __shared__ int   pay_s[4][64];
  __shared__ float w_s[4][64 * WH];
  int is32 = flags[0];
  int wv   = threadIdx.x >> 6;
  int lane = threadIdx.x & 63;
  int n = blockIdx.x * 4 + wv;
  int rs = offs[n], re = offs[n + 1];
  rs = max(rs, 0); re = min(re, E);
  const int myh = (H == 1) ? 0 : (lane >> 4);   // OUTC=192: lane*12/192 = lane/16

  float m_run[H], z_run[H], acc[12];
#pragma unroll
  for (int h = 0; h < H; ++h){ m_run[h] = -__builtin_inff(); z_run[h] = 0.f; }
#pragma unroll
  for (int i = 0; i < 12; ++i) acc[i] = 0.f;

  for (int base = rs; base < re; base += 64){
    int dc = min(64, re - base);
    int pay = 0;
    float al[H];
#pragma unroll
    for (int h = 0; h < H; ++h) al[h] = -__builtin_inff();
    if (lane < dc){
      pay = payload[base + lane];
      int et = pay >> 16, src = pay & 0xffff;
      if (H == 4){
        f32x4 qv = *(const f32x4*)(qn + ((size_t)et * nN + n)   * 4);
        f32x4 kv = *(const f32x4*)(kn + ((size_t)et * nN + src) * 4);
#pragma unroll
        for (int h = 0; h < H; ++h){
          float a = qv[h & 3] + kv[h & 3];
          al[h] = (a > 0.f) ? a : 0.2f * a;
        }
      } else {
        float a = qn[((size_t)et * nN + n) * 4] + kn[((size_t)et * nN + src) * 4];
        al[0] = (a > 0.f) ? a : 0.2f * a;
      }
    }
    // online-softmax chunk update
    float scs[H], wgt[H];
#pragma unroll
    for (int h = 0; h < H; ++h){
      float v = al[h];
      for (int off = 32; off; off >>= 1) v = fmaxf(v, __shfl_xor(v, off));
      float nm = fmaxf(m_run[h], v);
      scs[h] = (m_run[h] == -__builtin_inff()) ? 0.f : expf(m_run[h] - nm);
      m_run[h] = nm;
      wgt[h] = (lane < dc) ? expf(al[h] - nm) : 0.f;
      float s = wgt[h];
      for (int off = 32; off; off >>= 1) s += __shfl_xor(s, off);
      z_run[h] = z_run[h] * scs[h] + s;
    }
    float msc = sel<H>(scs, myh);
#pragma unroll
    for (int i = 0; i < 12; ++i) acc[i] *= msc;

    // stash chunk data in per-wave LDS (same-wave DS ops are in-order)
    if (lane < dc){
      pay_s[wv][lane] = pay;
#pragma unroll
      for (int h = 0; h < WH; ++h) w_s[wv][lane * WH + h] = wgt[h];
    }

    // batched gather-accumulate: 4 edges -> 12 loads in flight
    for (int j0 = 0; j0 < dc; j0 += 4){
      uint2 c[4][3];
      float w4[4];
#pragma unroll
      for (int u = 0; u < 4; ++u){
        int jc = j0 + u;
        int ok = jc < dc;
        int jl2 = ok ? jc : j0;
        int pj = pay_s[wv][jl2];
        float ww = w_s[wv][jl2 * WH + ((H == 1) ? 0 : myh)];
        w4[u] = ok ? ww : 0.f;
        int et = pj >> 16, src = pj & 0xffff;
        const uint2* rp = (const uint2*)(xr + ((size_t)et * nN + src) * DIM + lane * 12);
        c[u][0] = rp[0]; c[u][1] = rp[1]; c[u][2] = rp[2];
      }
#pragma unroll
      for (int u = 0; u < 4; ++u){
        float wj = w4[u];
        acc[0]  += wj * bfl(c[u][0].x); acc[1]  += wj * bfh(c[u][0].x);
        acc[2]  += wj * bfl(c[u][0].y); acc[3]  += wj * bfh(c[u][0].y);
        acc[4]  += wj * bfl(c[u][1].x); acc[5]  += wj * bfh(c[u][1].x);
        acc[6]  += wj * bfl(c[u][1].y); acc[7]  += wj * bfh(c[u][1].y);
        acc[8]  += wj * bfl(c[u][2].x); acc[9]  += wj * bfh(c[u][2].x);
        acc[10] += wj * bfl(c[u][2].y); acc[11] += wj * bfh(c[u][2].y);
      }
    }
  }

  float inv = 1.0f / (sel<H>(z_run, myh) + 1e-16f);
  float o[12];
#pragma unroll
  for (int i = 0; i < 12; ++i){
    float v = acc[i] * inv + ldf(bias, (size_t)lane * 12 + i, is32);
    if (ELU) v = (v > 0.f) ? v : (expf(v) - 1.f);
    o[i] = v;
  }
  if (OUT32 && is32){
    float* op = (float*)outp + (size_t)n * DIM + lane * 12;
    float4 f0 = {o[0], o[1], o[2],  o[3]};
    float4 f1 = {o[4], o[5], o[6],  o[7]};
    float4 f2 = {o[8], o[9], o[10], o[11]};
    ((float4*)op)[0] = f0; ((float4*)op)[1] = f1; ((float4*)op)[2] = f2;
  } else {
    uint2* op = (uint2*)((unsigned short*)outp + (size_t)n * DIM + lane * 12);
    uint2 s0, s1, s2;
    s0.x = pck(o[0], o[1]);  s0.y = pck(o[2], o[3]);
    s1.x = pck(o[4], o[5]);  s1.y = pck(o[6], o[7]);
    s2.x = pck(o[8], o[9]);  s2.y = pck(o[10], o[11]);
    op[0] = s0; op[1] = s1; op[2] = s2;
  }
}

// ---------------- launcher ----------------
extern "C" void kernel_launch(void* const* d_in, const int* in_sizes, int n_in,
                              void* d_out, int out_size, void* d_ws, size_t ws_size,
                              hipStream_t stream){
  const void* x   = d_in[0];
  const void* ei  = d_in[1];
  const void* ety = d_in[2];
  const void* W1  = d_in[3];
  const void* q1  = d_in[4];
  const void* k1  = d_in[5];
  const void* b1  = d_in[6];
  const void* W2  = d_in[7];
  const void* q2  = d_in[8];
  const void* k2  = d_in[9];
  const void* b2  = d_in[10];

  int nN = in_sizes[0] / DIM;   // 32768
  int E  = in_sizes[2];         // 160000

  char* ws = (char*)d_ws;
  size_t off = 0;
  auto alloc = [&](size_t bytes) -> void* {
    void* p = ws + off;
    off += (bytes + 255) & ~(size_t)255;
    return p;
  };
  unsigned short* xr   = (unsigned short*)alloc((size_t)NREL * nN * DIM * 2);
  unsigned short* xb   = (unsigned short*)alloc((size_t)nN * DIM * 2);
  unsigned short* h    = (unsigned short*)alloc((size_t)nN * DIM * 2);
  unsigned short* Wt   = (unsigned short*)alloc((size_t)NREL * DIM * DIM * 2);
  unsigned short* Wqkb = (unsigned short*)alloc((size_t)DIM * 32 * 2);
  unsigned short* Bpk  = (unsigned short*)alloc((size_t)3072 * 16);
  float* qn  = (float*)alloc((size_t)NREL * nN * 4 * 4);
  float* kn  = (float*)alloc((size_t)NREL * nN * 4 * 4);
  int* offs    = (int*)alloc((size_t)(nN + 1) * 4);
  int* cursor  = (int*)alloc((size_t)nN * 4);
  int* counts  = (int*)alloc((size_t)nN * 4);
  int* payload = (int*)alloc((size_t)E * 4);
  int* flags   = (int*)alloc(16);

  detect_kernel<<<1, 256, 0, stream>>>((const unsigned short*)x, (const unsigned*)ei,
                                       (const unsigned*)ety, flags);
  convert_x<<<(nN * DIM / 4 + 255) / 256, 256, 0, stream>>>(x, xb, flags, nN * DIM / 4);

  hipMemsetAsync(counts, 0, (size_t)nN * 4, stream);
  hist_kernel<<<(E + 255) / 256, 256, 0, stream>>>(ei, counts, flags, E);
  scan_kernel<<<1, 1024, 0, stream>>>(counts, offs, cursor, nN);
  scatter_kernel<<<(E + 255) / 256, 256, 0, stream>>>(ei, ety, cursor, payload, flags, E);

  dim3 tg(DIM / 32, DIM / 32, NREL), tb(32, 8);
  int gemm_blocks = 8 * (16 * 18);   // 2304: 128 m-tiles x 18 (r,bn)

  // ---- layer 1 (H=4, ELU) ----
  transpose_w<<<tg, tb, 0, stream>>>(W1, Wt, flags);
  hipMemsetAsync(Wqkb, 0, (size_t)DIM * 32 * 2, stream);
  wqk_kernel<4><<<(NREL * DIM) / 4, 256, 0, stream>>>(W1, q1, k1, Wqkb, flags);
  pack_b<<<12, 256, 0, stream>>>(Wqkb, Bpk);
  qnkn_mfma<<<nN / 64, 256, 0, stream>>>(xb, Bpk, qn, kn, nN);
  gemm_bf16<<<gemm_blocks, 256, 0, stream>>>(xb, Wt, xr, nN);
  agg_kernel<4, true, false><<<nN / 4, 256, 0, stream>>>(xr, qn, kn, offs, payload, b1, h,
                                                         flags, nN, E);

  // ---- layer 2 (H=1, no activation) ----
  transpose_w<<<tg, tb, 0, stream>>>(W2, Wt, flags);
  hipMemsetAsync(Wqkb, 0, (size_t)DIM * 32 * 2, stream);
  wqk_kernel<1><<<(NREL * DIM) / 4, 256, 0, stream>>>(W2, q2, k2, Wqkb, flags);
  pack_b<<<12, 256, 0, stream>>>(Wqkb, Bpk);
  qnkn_mfma<<<nN / 64, 256, 0, stream>>>(h, Bpk, qn, kn, nN);
  gemm_bf16<<<gemm_blocks, 256, 0, stream>>>(h, Wt, xr, nN);
  agg_kernel<1, false, true><<<nN / 4, 256, 0, stream>>>(xr, qn, kn, offs, payload, b2,
                                                         d_out, flags, nN, E);
}